// Round 3
// baseline (208.433 us; speedup 1.0000x reference)
//
#include <hip/hip_runtime.h>
#include <hip/hip_bf16.h>
#include <stdint.h>
#include <stddef.h>

// DecoderAttention: B=2,T=2048,C=1024,H=16,D=64, causal, p=0.0
// R3: (1) gemm_qkv coalesced epilogue via LDS C-tile (fixes V transpose scatter
//     and scalar bf16 stores -> bf16x8 stores); (2) flash attention Q-tile 128
//     (wave owns 32 q-rows, K/V LDS reads shared across both m-frags -> LDS-pipe
//     traffic per FLOP down ~1.5x, barriers halved); (3) gemm_out 64x128 tiles
//     for 2 blocks/CU.

typedef __bf16 bf16;
typedef __attribute__((ext_vector_type(8))) __bf16 bf16x8;
typedef __attribute__((ext_vector_type(4))) __bf16 bf16x4;
typedef __attribute__((ext_vector_type(4))) float floatx4;

#define MFMA_16x16x32(A, B, C) __builtin_amdgcn_mfma_f32_16x16x32_bf16(A, B, C, 0, 0, 0)

static constexpr int T_SEQ = 2048;
static constexpr int CDIM  = 1024;

// async 16B global->LDS. LDS dest MUST be wave-uniform-base + lane*16.
__device__ __forceinline__ void gl2lds16(const bf16* g, bf16* l) {
  __builtin_amdgcn_global_load_lds(
      (const __attribute__((address_space(1))) uint32_t*)g,
      (__attribute__((address_space(3))) uint32_t*)l, 16, 0, 0);
}

// ---------------------------------------------------------------------------
// fp32 -> bf16 conversion / packing.
__global__ __launch_bounds__(256) void convert_kernel(
    const float* __restrict__ x, const float* __restrict__ Wq,
    const float* __restrict__ Wk, const float* __restrict__ Wv,
    const float* __restrict__ Wo,
    bf16* __restrict__ Xb, bf16* __restrict__ Wqkvb, bf16* __restrict__ Wob) {
  size_t i = ((size_t)blockIdx.x * 256 + threadIdx.x) * 4;  // 8388608 total elems
  const float* src;
  bf16* dst;
  size_t off;
  if (i < 4194304) {
    src = x; dst = Xb; off = i;
  } else {
    size_t r = i - 4194304;
    int wsel = (int)(r >> 20);
    off = r & 1048575;
    src = (wsel == 0) ? Wq : (wsel == 1) ? Wk : (wsel == 2) ? Wv : Wo;
    dst = (wsel < 3) ? (Wqkvb + ((size_t)wsel << 20)) : Wob;
  }
  float4 v = *(const float4*)(src + off);
  bf16x4 o;
  o[0] = (bf16)v.x; o[1] = (bf16)v.y; o[2] = (bf16)v.z; o[3] = (bf16)v.w;
  *(bf16x4*)(dst + off) = o;
}

// ---------------------------------------------------------------------------
// Shared 128x128-tile GEMM mainloop: C = A[M,K] * B[N,K]^T  (both bf16, K-contig)
__device__ __forceinline__ void gemm_tile_128x128(
    const bf16* __restrict__ A, const bf16* __restrict__ B, int K,
    bf16* As, bf16* Bs, floatx4 (&acc)[4][4], int bM, int bN) {
  const int tid = threadIdx.x;
  const int w = tid >> 6, l = tid & 63;
  const int wm = w & 1, wn = w >> 1;
  const int lr = l >> 3, cl = l & 7;   // staging: row-in-group, 16B chunk
  const int fr = l & 15, q4 = l >> 4;  // frag row, quad

#pragma unroll
  for (int mi = 0; mi < 4; ++mi)
#pragma unroll
    for (int ni = 0; ni < 4; ++ni)
#pragma unroll
      for (int r = 0; r < 4; ++r) acc[mi][ni][r] = 0.0f;

  for (int k0 = 0; k0 < K; k0 += 64) {
#pragma unroll
    for (int i = 0; i < 4; ++i) {
      int row = i * 32 + w * 8 + lr;
      int cg = cl ^ (row & 7);  // swizzled source chunk
      gl2lds16(A + (size_t)(bM * 128 + row) * K + k0 + cg * 8,
               As + row * 64 + cl * 8);
      gl2lds16(B + (size_t)(bN * 128 + row) * K + k0 + cg * 8,
               Bs + row * 64 + cl * 8);
    }
    __syncthreads();
#pragma unroll
    for (int kk = 0; kk < 2; ++kk) {
      const int cgk = kk * 4 + q4;
      bf16x8 af[4], bfr[4];
#pragma unroll
      for (int mi = 0; mi < 4; ++mi) {
        int row = wm * 64 + mi * 16 + fr;
        af[mi] = *(const bf16x8*)(As + row * 64 + (cgk ^ (row & 7)) * 8);
      }
#pragma unroll
      for (int ni = 0; ni < 4; ++ni) {
        int row = wn * 64 + ni * 16 + fr;
        bfr[ni] = *(const bf16x8*)(Bs + row * 64 + (cgk ^ (row & 7)) * 8);
      }
#pragma unroll
      for (int mi = 0; mi < 4; ++mi)
#pragma unroll
        for (int ni = 0; ni < 4; ++ni)
          acc[mi][ni] = MFMA_16x16x32(af[mi], bfr[ni], acc[mi][ni]);
    }
    __syncthreads();
  }
}

// ---------------------------------------------------------------------------
// Kernel 2: fused QKV projection, coalesced epilogue through LDS.
// Q pre-scaled by (1/8)*log2(e); V stored transposed [B,H,D,T].
__global__ __launch_bounds__(256) void gemm_qkv(
    const bf16* __restrict__ Xb, const bf16* __restrict__ Wqkvb,
    const float* __restrict__ bq, const float* __restrict__ bk,
    const float* __restrict__ bv,
    bf16* __restrict__ Qb, bf16* __restrict__ Kb, bf16* __restrict__ Vtb) {
  __shared__ __align__(16) bf16 smem[17408];  // 34.8 KB: As(8192)+Bs(8192) / Cs(128x136)
  bf16* As = smem;
  bf16* Bs = smem + 8192;
  bf16* Cs = smem;  // overlaid; used only after the tile loop's final barrier
  floatx4 acc[4][4];
  const int bM = blockIdx.x & 31;   // 32 M-tiles (4096/128)
  const int bN = blockIdx.x >> 5;   // 24 N-tiles (3072/128)
  gemm_tile_128x128(Xb, Wqkvb, CDIM, As, Bs, acc, bM, bN);

  const int tid = threadIdx.x;
  const int w = tid >> 6, l = tid & 63;
  const int wm = w & 1, wn = w >> 1;
  const int fc = l & 15, q4 = l >> 4;
  const int seg = bN >> 3;  // 0=Q, 1=K, 2=V (uniform per block)
  const float QSCALE = 0.125f * 1.44269504089f;
  const float* bp = (seg == 0) ? bq : (seg == 1) ? bk : bv;

  // acc (C-layout) -> Cs. Q/K: Cs[tt][j]; V: Cs[j][tt] (transposed). stride 136.
#pragma unroll
  for (int ni = 0; ni < 4; ++ni) {
    int jl = wn * 64 + ni * 16 + fc;
    float bias = bp[(bN * 128 + jl) & 1023];
#pragma unroll
    for (int mi = 0; mi < 4; ++mi)
#pragma unroll
      for (int r = 0; r < 4; ++r) {
        int ttl = wm * 64 + mi * 16 + q4 * 4 + r;
        float val = acc[mi][ni][r] + bias;
        if (seg == 0) val *= QSCALE;
        int addr = (seg == 2) ? jl * 136 + ttl : ttl * 136 + jl;
        Cs[addr] = (bf16)val;
      }
  }
  __syncthreads();

  // coalesced read-back: thread = (major-group, 16B minor chunk)
  const int chunk = tid & 15;        // minor: 8 elems
  const int rb = (tid >> 4) * 8;     // major: 8 rows
  if (seg < 2) {
    bf16* basep = (seg == 0) ? Qb : Kb;
#pragma unroll
    for (int u = 0; u < 8; ++u) {
      int maj = rb + u;  // tt_local
      bf16x8 vdat = *(const bf16x8*)(Cs + maj * 136 + chunk * 8);
      int n = bM * 128 + maj;
      int b = n >> 11, tt = n & 2047;
      int j = bN * 128 + chunk * 8;
      int h = (j >> 6) & 15, d = j & 63;
      *(bf16x8*)(basep + (((size_t)(b * 16 + h) * T_SEQ + tt) << 6) + d) = vdat;
    }
  } else {
#pragma unroll
    for (int u = 0; u < 8; ++u) {
      int maj = rb + u;  // j_local
      bf16x8 vdat = *(const bf16x8*)(Cs + maj * 136 + chunk * 8);
      int j = bN * 128 + maj;
      int h = (j >> 6) & 15, d = j & 63;
      int n0 = bM * 128 + chunk * 8;
      int b = n0 >> 11, tt0 = n0 & 2047;
      *(bf16x8*)(Vtb + ((size_t)(b * 16 + h) * 64 + d) * T_SEQ + tt0) = vdat;
    }
  }
}

// ---------------------------------------------------------------------------
// Kernel 3: causal flash attention, no-max exp2 softmax, Q-tile = 128 rows.
// Grid (B*H, T/128). Block = 4 waves; wave w owns rows {qbase + mi*64 + w*16}.
__global__ __launch_bounds__(256) void flash_attn(
    const bf16* __restrict__ Qb, const bf16* __restrict__ Kb,
    const bf16* __restrict__ Vtb, bf16* __restrict__ Ao) {
  __shared__ __align__(16) bf16 Ks[64 * 64];
  __shared__ __align__(16) bf16 Vs[64 * 64];
  __shared__ __align__(16) bf16 Ps[4][2][16 * 72];

  const int bh = blockIdx.x;   // b*16+h
  const int qt2 = blockIdx.y;  // 0..15
  const int b = bh >> 4, h = bh & 15;
  const int tid = threadIdx.x;
  const int w = tid >> 6, l = tid & 63;
  const int fc = l & 15, q4 = l >> 4;
  const int lr = l >> 3, cl = l & 7;

  const bf16* Qg = Qb + (size_t)bh * T_SEQ * 64;
  const bf16* Kg = Kb + (size_t)bh * T_SEQ * 64;
  const bf16* Vg = Vtb + (size_t)bh * 64 * T_SEQ;
  const int qbase = qt2 * 128;

  // Q A-frags (already scaled by (1/8)*log2e)
  bf16x8 qf[2][2];
#pragma unroll
  for (int mi = 0; mi < 2; ++mi) {
    const bf16* qrow = Qg + (size_t)(qbase + mi * 64 + w * 16 + fc) * 64;
#pragma unroll
    for (int kk = 0; kk < 2; ++kk)
      qf[mi][kk] = *(const bf16x8*)(qrow + kk * 32 + q4 * 8);
  }

  bf16x8 ones;
#pragma unroll
  for (int i = 0; i < 8; ++i) ones[i] = (bf16)1.0f;

  floatx4 o[2][4];
  floatx4 lacc[2];
#pragma unroll
  for (int mi = 0; mi < 2; ++mi) {
#pragma unroll
    for (int ds = 0; ds < 4; ++ds)
#pragma unroll
      for (int r = 0; r < 4; ++r) o[mi][ds][r] = 0.0f;
#pragma unroll
    for (int r = 0; r < 4; ++r) lacc[mi][r] = 0.0f;
  }

  const int kvmax = 2 * qt2 + 1;
  for (int kv = 0; kv <= kvmax; ++kv) {
    const int kvbase = kv * 64;
#pragma unroll
    for (int i = 0; i < 2; ++i) {
      int row = i * 32 + w * 8 + lr;
      int cg = cl ^ (row & 7);
      gl2lds16(Kg + (size_t)(kvbase + row) * 64 + cg * 8, Ks + row * 64 + cl * 8);
      gl2lds16(Vg + (size_t)row * T_SEQ + kvbase + cg * 8, Vs + row * 64 + cl * 8);
    }
    __syncthreads();

    const bool skip0 = (kv == 2 * qt2 + 1);  // m0 fully above diagonal

    // S = Q K^T; kf shared across both m-frags
    floatx4 s[2][4];
#pragma unroll
    for (int mi = 0; mi < 2; ++mi)
#pragma unroll
      for (int ni = 0; ni < 4; ++ni)
#pragma unroll
        for (int r = 0; r < 4; ++r) s[mi][ni][r] = 0.0f;
#pragma unroll
    for (int kk = 0; kk < 2; ++kk) {
      const int cgk = kk * 4 + q4;
#pragma unroll
      for (int ni = 0; ni < 4; ++ni) {
        int row = ni * 16 + fc;
        bf16x8 kf = *(const bf16x8*)(Ks + row * 64 + (cgk ^ (row & 7)) * 8);
        if (!skip0) s[0][ni] = MFMA_16x16x32(qf[0][kk], kf, s[0][ni]);
        s[1][ni] = MFMA_16x16x32(qf[1][kk], kf, s[1][ni]);
      }
    }

    // P = exp2(S) (no max: logits O(10), fp32-safe); mask on diagonal tile.
#pragma unroll
    for (int mi = 0; mi < 2; ++mi) {
      if (mi == 0 && skip0) continue;
      const bool diag = (kv == 2 * qt2 + mi);
      if (diag) {
        int qc = w * 16 + q4 * 4;
#pragma unroll
        for (int ni = 0; ni < 4; ++ni)
#pragma unroll
          for (int r = 0; r < 4; ++r) {
            int kc = ni * 16 + fc;
            float p = (kc > qc + r) ? 0.0f : __builtin_amdgcn_exp2f(s[mi][ni][r]);
            Ps[w][mi][(q4 * 4 + r) * 72 + ni * 16 + fc] = (bf16)p;
          }
      } else {
#pragma unroll
        for (int ni = 0; ni < 4; ++ni)
#pragma unroll
          for (int r = 0; r < 4; ++r)
            Ps[w][mi][(q4 * 4 + r) * 72 + ni * 16 + fc] =
                (bf16)__builtin_amdgcn_exp2f(s[mi][ni][r]);
      }
    }

    // O += P V ; l += P 1 ; vf shared across both m-frags
#pragma unroll
    for (int kk = 0; kk < 2; ++kk) {
      const int cgk = kk * 4 + q4;
      bf16x8 pf0, pf1;
      if (!skip0) pf0 = *(const bf16x8*)(&Ps[w][0][fc * 72 + kk * 32 + q4 * 8]);
      pf1 = *(const bf16x8*)(&Ps[w][1][fc * 72 + kk * 32 + q4 * 8]);
#pragma unroll
      for (int ds = 0; ds < 4; ++ds) {
        int row = ds * 16 + fc;
        bf16x8 vf = *(const bf16x8*)(Vs + row * 64 + (cgk ^ (row & 7)) * 8);
        if (!skip0) o[0][ds] = MFMA_16x16x32(pf0, vf, o[0][ds]);
        o[1][ds] = MFMA_16x16x32(pf1, vf, o[1][ds]);
      }
      if (!skip0) lacc[0] = MFMA_16x16x32(pf0, ones, lacc[0]);
      lacc[1] = MFMA_16x16x32(pf1, ones, lacc[1]);
    }
    __syncthreads();
  }

  // epilogue: O/l -> AttnOut[B,T,C] bf16
#pragma unroll
  for (int mi = 0; mi < 2; ++mi) {
    float inv[4];
#pragma unroll
    for (int r = 0; r < 4; ++r) inv[r] = __builtin_amdgcn_rcpf(lacc[mi][r]);
#pragma unroll
    for (int ds = 0; ds < 4; ++ds)
#pragma unroll
      for (int r = 0; r < 4; ++r) {
        int tt = qbase + mi * 64 + w * 16 + q4 * 4 + r;
        int col = h * 64 + ds * 16 + fc;
        Ao[((size_t)(b * T_SEQ + tt) << 10) + col] = (bf16)(o[mi][ds][r] * inv[r]);
      }
  }
}

// ---------------------------------------------------------------------------
// Kernel 4: output projection, 64x128 tiles (512 blocks -> 2/CU), fp32 result
__global__ __launch_bounds__(256) void gemm_out(
    const bf16* __restrict__ Ab, const bf16* __restrict__ Wob,
    const float* __restrict__ bo, float* __restrict__ Y) {
  __shared__ __align__(16) bf16 As[64 * 64];    // 8 KB
  __shared__ __align__(16) bf16 Bs[128 * 64];   // 16 KB
  const int bM = blockIdx.x & 63;  // 64 M-tiles of 64 rows
  const int bN = blockIdx.x >> 6;  // 8 N-tiles of 128 cols
  const int tid = threadIdx.x;
  const int w = tid >> 6, l = tid & 63;
  const int wm = w & 1, wn = w >> 1;
  const int lr = l >> 3, cl = l & 7;
  const int fr = l & 15, q4 = l >> 4;
  const int fc = fr;

  floatx4 acc[2][4];
#pragma unroll
  for (int mi = 0; mi < 2; ++mi)
#pragma unroll
    for (int ni = 0; ni < 4; ++ni)
#pragma unroll
      for (int r = 0; r < 4; ++r) acc[mi][ni][r] = 0.0f;

  for (int k0 = 0; k0 < CDIM; k0 += 64) {
#pragma unroll
    for (int i = 0; i < 2; ++i) {
      int row = i * 32 + w * 8 + lr;
      int cg = cl ^ (row & 7);
      gl2lds16(Ab + (size_t)(bM * 64 + row) * CDIM + k0 + cg * 8,
               As + row * 64 + cl * 8);
    }
#pragma unroll
    for (int i = 0; i < 4; ++i) {
      int row = i * 32 + w * 8 + lr;
      int cg = cl ^ (row & 7);
      gl2lds16(Wob + (size_t)(bN * 128 + row) * CDIM + k0 + cg * 8,
               Bs + row * 64 + cl * 8);
    }
    __syncthreads();
#pragma unroll
    for (int kk = 0; kk < 2; ++kk) {
      const int cgk = kk * 4 + q4;
      bf16x8 af[2], bfr[4];
#pragma unroll
      for (int mi = 0; mi < 2; ++mi) {
        int row = wm * 32 + mi * 16 + fr;
        af[mi] = *(const bf16x8*)(As + row * 64 + (cgk ^ (row & 7)) * 8);
      }
#pragma unroll
      for (int ni = 0; ni < 4; ++ni) {
        int row = wn * 64 + ni * 16 + fr;
        bfr[ni] = *(const bf16x8*)(Bs + row * 64 + (cgk ^ (row & 7)) * 8);
      }
#pragma unroll
      for (int mi = 0; mi < 2; ++mi)
#pragma unroll
        for (int ni = 0; ni < 4; ++ni)
          acc[mi][ni] = MFMA_16x16x32(af[mi], bfr[ni], acc[mi][ni]);
    }
    __syncthreads();
  }

#pragma unroll
  for (int ni = 0; ni < 4; ++ni) {
    int j = bN * 128 + wn * 64 + ni * 16 + fc;
    float bias = bo[j];
#pragma unroll
    for (int mi = 0; mi < 2; ++mi)
#pragma unroll
      for (int r = 0; r < 4; ++r) {
        int n = bM * 64 + wm * 32 + mi * 16 + q4 * 4 + r;
        Y[(size_t)n * CDIM + j] = acc[mi][ni][r] + bias;
      }
  }
}

// ---------------------------------------------------------------------------
extern "C" void kernel_launch(void* const* d_in, const int* in_sizes, int n_in,
                              void* d_out, int out_size, void* d_ws, size_t ws_size,
                              hipStream_t stream) {
  const float* x  = (const float*)d_in[0];
  const float* Wq = (const float*)d_in[1];
  const float* bq = (const float*)d_in[2];
  const float* Wk = (const float*)d_in[3];
  const float* bk = (const float*)d_in[4];
  const float* Wv = (const float*)d_in[5];
  const float* bv = (const float*)d_in[6];
  const float* Wo = (const float*)d_in[7];
  const float* bo = (const float*)d_in[8];
  float* Y = (float*)d_out;

  char* ws = (char*)d_ws;
  const size_t MB = 1024 * 1024;
  bf16* Xb    = (bf16*)(ws + 0);        //  8 MB  [4096,1024]
  bf16* Wqkvb = (bf16*)(ws + 8 * MB);   //  6 MB  [3072,1024]
  bf16* Wob   = (bf16*)(ws + 14 * MB);  //  2 MB  [1024,1024]
  bf16* Qb    = (bf16*)(ws + 16 * MB);  //  8 MB  [B,H,T,D] (pre-scaled, log2 domain)
  bf16* Kb    = (bf16*)(ws + 24 * MB);  //  8 MB  [B,H,T,D]
  bf16* Vtb   = (bf16*)(ws + 32 * MB);  //  8 MB  [B,H,D,T]
  bf16* Ao    = Xb;                     //  reuse: Xb dead after gemm_qkv

  convert_kernel<<<8192, 256, 0, stream>>>(x, Wq, Wk, Wv, Wo, Xb, Wqkvb, Wob);
  gemm_qkv<<<32 * 24, 256, 0, stream>>>(Xb, Wqkvb, bq, bk, bv, Qb, Kb, Vtb);
  flash_attn<<<dim3(32, 16), 256, 0, stream>>>(Qb, Kb, Vtb, Ao);
  gemm_out<<<64 * 8, 256, 0, stream>>>(Ao, Wob, bo, Y);
}

// Round 4
// 189.212 us; speedup vs baseline: 1.1016x; 1.1016x over previous
//
#include <hip/hip_runtime.h>
#include <hip/hip_bf16.h>
#include <stdint.h>
#include <stddef.h>

// DecoderAttention: B=2,T=2048,C=1024,H=16,D=64, causal, p=0.0
// R4: flash back to 64-row Q tiles (1024 blocks -> 4 blocks/CU; R3's 128-row
//     tile starved the CUs at 2 waves/SIMD, latency-bound with all pipes <23%)
//     + longest-first dispatch order (qt = 31 - blockIdx.y) so the 32-iter
//     causal blocks start at t=0 and short blocks backfill.
//     gemm_qkv keeps R3's coalesced LDS epilogue; gemm_out keeps 64x128 tiles.

typedef __bf16 bf16;
typedef __attribute__((ext_vector_type(8))) __bf16 bf16x8;
typedef __attribute__((ext_vector_type(4))) __bf16 bf16x4;
typedef __attribute__((ext_vector_type(4))) float floatx4;

#define MFMA_16x16x32(A, B, C) __builtin_amdgcn_mfma_f32_16x16x32_bf16(A, B, C, 0, 0, 0)

static constexpr int T_SEQ = 2048;
static constexpr int CDIM  = 1024;

// async 16B global->LDS. LDS dest MUST be wave-uniform-base + lane*16.
__device__ __forceinline__ void gl2lds16(const bf16* g, bf16* l) {
  __builtin_amdgcn_global_load_lds(
      (const __attribute__((address_space(1))) uint32_t*)g,
      (__attribute__((address_space(3))) uint32_t*)l, 16, 0, 0);
}

// ---------------------------------------------------------------------------
// fp32 -> bf16 conversion / packing.
__global__ __launch_bounds__(256) void convert_kernel(
    const float* __restrict__ x, const float* __restrict__ Wq,
    const float* __restrict__ Wk, const float* __restrict__ Wv,
    const float* __restrict__ Wo,
    bf16* __restrict__ Xb, bf16* __restrict__ Wqkvb, bf16* __restrict__ Wob) {
  size_t i = ((size_t)blockIdx.x * 256 + threadIdx.x) * 4;  // 8388608 total elems
  const float* src;
  bf16* dst;
  size_t off;
  if (i < 4194304) {
    src = x; dst = Xb; off = i;
  } else {
    size_t r = i - 4194304;
    int wsel = (int)(r >> 20);
    off = r & 1048575;
    src = (wsel == 0) ? Wq : (wsel == 1) ? Wk : (wsel == 2) ? Wv : Wo;
    dst = (wsel < 3) ? (Wqkvb + ((size_t)wsel << 20)) : Wob;
  }
  float4 v = *(const float4*)(src + off);
  bf16x4 o;
  o[0] = (bf16)v.x; o[1] = (bf16)v.y; o[2] = (bf16)v.z; o[3] = (bf16)v.w;
  *(bf16x4*)(dst + off) = o;
}

// ---------------------------------------------------------------------------
// Shared 128x128-tile GEMM mainloop: C = A[M,K] * B[N,K]^T  (both bf16, K-contig)
__device__ __forceinline__ void gemm_tile_128x128(
    const bf16* __restrict__ A, const bf16* __restrict__ B, int K,
    bf16* As, bf16* Bs, floatx4 (&acc)[4][4], int bM, int bN) {
  const int tid = threadIdx.x;
  const int w = tid >> 6, l = tid & 63;
  const int wm = w & 1, wn = w >> 1;
  const int lr = l >> 3, cl = l & 7;   // staging: row-in-group, 16B chunk
  const int fr = l & 15, q4 = l >> 4;  // frag row, quad

#pragma unroll
  for (int mi = 0; mi < 4; ++mi)
#pragma unroll
    for (int ni = 0; ni < 4; ++ni)
#pragma unroll
      for (int r = 0; r < 4; ++r) acc[mi][ni][r] = 0.0f;

  for (int k0 = 0; k0 < K; k0 += 64) {
#pragma unroll
    for (int i = 0; i < 4; ++i) {
      int row = i * 32 + w * 8 + lr;
      int cg = cl ^ (row & 7);  // swizzled source chunk
      gl2lds16(A + (size_t)(bM * 128 + row) * K + k0 + cg * 8,
               As + row * 64 + cl * 8);
      gl2lds16(B + (size_t)(bN * 128 + row) * K + k0 + cg * 8,
               Bs + row * 64 + cl * 8);
    }
    __syncthreads();
#pragma unroll
    for (int kk = 0; kk < 2; ++kk) {
      const int cgk = kk * 4 + q4;
      bf16x8 af[4], bfr[4];
#pragma unroll
      for (int mi = 0; mi < 4; ++mi) {
        int row = wm * 64 + mi * 16 + fr;
        af[mi] = *(const bf16x8*)(As + row * 64 + (cgk ^ (row & 7)) * 8);
      }
#pragma unroll
      for (int ni = 0; ni < 4; ++ni) {
        int row = wn * 64 + ni * 16 + fr;
        bfr[ni] = *(const bf16x8*)(Bs + row * 64 + (cgk ^ (row & 7)) * 8);
      }
#pragma unroll
      for (int mi = 0; mi < 4; ++mi)
#pragma unroll
        for (int ni = 0; ni < 4; ++ni)
          acc[mi][ni] = MFMA_16x16x32(af[mi], bfr[ni], acc[mi][ni]);
    }
    __syncthreads();
  }
}

// ---------------------------------------------------------------------------
// Kernel 2: fused QKV projection, coalesced epilogue through LDS.
// Q pre-scaled by (1/8)*log2(e); V stored transposed [B,H,D,T].
__global__ __launch_bounds__(256) void gemm_qkv(
    const bf16* __restrict__ Xb, const bf16* __restrict__ Wqkvb,
    const float* __restrict__ bq, const float* __restrict__ bk,
    const float* __restrict__ bv,
    bf16* __restrict__ Qb, bf16* __restrict__ Kb, bf16* __restrict__ Vtb) {
  __shared__ __align__(16) bf16 smem[17408];  // 34.8 KB: As(8192)+Bs(8192) / Cs(128x136)
  bf16* As = smem;
  bf16* Bs = smem + 8192;
  bf16* Cs = smem;  // overlaid; used only after the tile loop's final barrier
  floatx4 acc[4][4];
  const int bM = blockIdx.x & 31;   // 32 M-tiles (4096/128)
  const int bN = blockIdx.x >> 5;   // 24 N-tiles (3072/128)
  gemm_tile_128x128(Xb, Wqkvb, CDIM, As, Bs, acc, bM, bN);

  const int tid = threadIdx.x;
  const int w = tid >> 6, l = tid & 63;
  const int wm = w & 1, wn = w >> 1;
  const int fc = l & 15, q4 = l >> 4;
  const int seg = bN >> 3;  // 0=Q, 1=K, 2=V (uniform per block)
  const float QSCALE = 0.125f * 1.44269504089f;
  const float* bp = (seg == 0) ? bq : (seg == 1) ? bk : bv;

  // acc (C-layout) -> Cs. Q/K: Cs[tt][j]; V: Cs[j][tt] (transposed). stride 136.
#pragma unroll
  for (int ni = 0; ni < 4; ++ni) {
    int jl = wn * 64 + ni * 16 + fc;
    float bias = bp[(bN * 128 + jl) & 1023];
#pragma unroll
    for (int mi = 0; mi < 4; ++mi)
#pragma unroll
      for (int r = 0; r < 4; ++r) {
        int ttl = wm * 64 + mi * 16 + q4 * 4 + r;
        float val = acc[mi][ni][r] + bias;
        if (seg == 0) val *= QSCALE;
        int addr = (seg == 2) ? jl * 136 + ttl : ttl * 136 + jl;
        Cs[addr] = (bf16)val;
      }
  }
  __syncthreads();

  // coalesced read-back: thread = (major-group, 16B minor chunk)
  const int chunk = tid & 15;        // minor: 8 elems
  const int rb = (tid >> 4) * 8;     // major: 8 rows
  if (seg < 2) {
    bf16* basep = (seg == 0) ? Qb : Kb;
#pragma unroll
    for (int u = 0; u < 8; ++u) {
      int maj = rb + u;  // tt_local
      bf16x8 vdat = *(const bf16x8*)(Cs + maj * 136 + chunk * 8);
      int n = bM * 128 + maj;
      int b = n >> 11, tt = n & 2047;
      int j = bN * 128 + chunk * 8;
      int h = (j >> 6) & 15, d = j & 63;
      *(bf16x8*)(basep + (((size_t)(b * 16 + h) * T_SEQ + tt) << 6) + d) = vdat;
    }
  } else {
#pragma unroll
    for (int u = 0; u < 8; ++u) {
      int maj = rb + u;  // j_local
      bf16x8 vdat = *(const bf16x8*)(Cs + maj * 136 + chunk * 8);
      int j = bN * 128 + maj;
      int h = (j >> 6) & 15, d = j & 63;
      int n0 = bM * 128 + chunk * 8;
      int b = n0 >> 11, tt0 = n0 & 2047;
      *(bf16x8*)(Vtb + ((size_t)(b * 16 + h) * 64 + d) * T_SEQ + tt0) = vdat;
    }
  }
}

// ---------------------------------------------------------------------------
// Kernel 3: causal flash attention, no-max exp2 softmax, Q-tile = 64 rows.
// Grid (B*H, T/64), longest-first: qt = 31 - blockIdx.y. 4 waves, wave w owns
// Q rows [qt*64 + w*16, +16). 25.6 KB LDS -> 4+ blocks/CU.
__global__ __launch_bounds__(256) void flash_attn(
    const bf16* __restrict__ Qb, const bf16* __restrict__ Kb,
    const bf16* __restrict__ Vtb, bf16* __restrict__ Ao) {
  __shared__ __align__(16) bf16 Ks[64 * 64];
  __shared__ __align__(16) bf16 Vs[64 * 64];
  __shared__ __align__(16) bf16 Ps[4][16 * 72];  // +8 pad

  const int bh = blockIdx.x;            // 0..31 = b*16+h
  const int qt = 31 - blockIdx.y;       // longest blocks dispatch first
  const int b = bh >> 4, h = bh & 15;
  const int tid = threadIdx.x;
  const int w = tid >> 6, l = tid & 63;
  const int fc = l & 15, q4 = l >> 4;
  const int lr = l >> 3, cl = l & 7;

  const bf16* Qg = Qb + (size_t)bh * T_SEQ * 64;
  const bf16* Kg = Kb + (size_t)bh * T_SEQ * 64;
  const bf16* Vg = Vtb + (size_t)bh * 64 * T_SEQ;

  // Q A-frags, loaded once (already scaled by (1/8)*log2e)
  const int qrow = qt * 64 + w * 16 + fc;
  bf16x8 qf[2];
  qf[0] = *(const bf16x8*)(Qg + (size_t)qrow * 64 + q4 * 8);
  qf[1] = *(const bf16x8*)(Qg + (size_t)qrow * 64 + 32 + q4 * 8);

  bf16x8 ones;
#pragma unroll
  for (int i = 0; i < 8; ++i) ones[i] = (bf16)1.0f;

  floatx4 o[4];
  floatx4 lacc;  // row-sum of P via MFMA ones-trick
#pragma unroll
  for (int ds = 0; ds < 4; ++ds)
#pragma unroll
    for (int r = 0; r < 4; ++r) o[ds][r] = 0.0f;
#pragma unroll
  for (int r = 0; r < 4; ++r) lacc[r] = 0.0f;

  for (int kv = 0; kv <= qt; ++kv) {
    const int kvbase = kv * 64;
#pragma unroll
    for (int i = 0; i < 2; ++i) {
      int row = i * 32 + w * 8 + lr;
      int cg = cl ^ (row & 7);
      gl2lds16(Kg + (size_t)(kvbase + row) * 64 + cg * 8, Ks + row * 64 + cl * 8);
      gl2lds16(Vg + (size_t)row * T_SEQ + kvbase + cg * 8, Vs + row * 64 + cl * 8);
    }
    __syncthreads();

    // S = Q K^T  (16 q-rows x 64 kv-cols per wave), log2 domain
    floatx4 s[4];
#pragma unroll
    for (int ni = 0; ni < 4; ++ni)
#pragma unroll
      for (int r = 0; r < 4; ++r) s[ni][r] = 0.0f;
#pragma unroll
    for (int kk = 0; kk < 2; ++kk) {
      const int cgk = kk * 4 + q4;
#pragma unroll
      for (int ni = 0; ni < 4; ++ni) {
        int row = ni * 16 + fc;
        bf16x8 kf = *(const bf16x8*)(Ks + row * 64 + (cgk ^ (row & 7)) * 8);
        s[ni] = MFMA_16x16x32(qf[kk], kf, s[ni]);
      }
    }

    // P = exp2(S) (no max: logits O(10), fp32-safe, shift-invariance exact);
    // masked entries p = 0. Write P to LDS in C-layout for A-frag re-read.
    if (kv == qt) {
      int qc = w * 16 + q4 * 4;
#pragma unroll
      for (int ni = 0; ni < 4; ++ni)
#pragma unroll
        for (int r = 0; r < 4; ++r) {
          int kc = ni * 16 + fc;
          float p = (kc > qc + r) ? 0.0f : __builtin_amdgcn_exp2f(s[ni][r]);
          Ps[w][(q4 * 4 + r) * 72 + ni * 16 + fc] = (bf16)p;
        }
    } else {
#pragma unroll
      for (int ni = 0; ni < 4; ++ni)
#pragma unroll
        for (int r = 0; r < 4; ++r)
          Ps[w][(q4 * 4 + r) * 72 + ni * 16 + fc] =
              (bf16)__builtin_amdgcn_exp2f(s[ni][r]);
    }

    // O += P V ; l += P 1  (row-sum on the idle MFMA pipe)
#pragma unroll
    for (int kk = 0; kk < 2; ++kk) {
      bf16x8 pf = *(const bf16x8*)(&Ps[w][fc * 72 + kk * 32 + q4 * 8]);
      const int cgk = kk * 4 + q4;
#pragma unroll
      for (int ds = 0; ds < 4; ++ds) {
        int row = ds * 16 + fc;
        bf16x8 vf = *(const bf16x8*)(Vs + row * 64 + (cgk ^ (row & 7)) * 8);
        o[ds] = MFMA_16x16x32(pf, vf, o[ds]);
      }
      lacc = MFMA_16x16x32(pf, ones, lacc);
    }
    __syncthreads();
  }

  // epilogue: O/l -> AttnOut[B,T,C] bf16
  float inv[4];
#pragma unroll
  for (int r = 0; r < 4; ++r) inv[r] = __builtin_amdgcn_rcpf(lacc[r]);
#pragma unroll
  for (int ds = 0; ds < 4; ++ds)
#pragma unroll
    for (int r = 0; r < 4; ++r) {
      int tt = qt * 64 + w * 16 + q4 * 4 + r;
      int col = h * 64 + ds * 16 + fc;
      Ao[((size_t)(b * T_SEQ + tt) << 10) + col] = (bf16)(o[ds][r] * inv[r]);
    }
}

// ---------------------------------------------------------------------------
// Kernel 4: output projection, 64x128 tiles (512 blocks -> 2/CU), fp32 result
__global__ __launch_bounds__(256) void gemm_out(
    const bf16* __restrict__ Ab, const bf16* __restrict__ Wob,
    const float* __restrict__ bo, float* __restrict__ Y) {
  __shared__ __align__(16) bf16 As[64 * 64];    // 8 KB
  __shared__ __align__(16) bf16 Bs[128 * 64];   // 16 KB
  const int bM = blockIdx.x & 63;  // 64 M-tiles of 64 rows
  const int bN = blockIdx.x >> 6;  // 8 N-tiles of 128 cols
  const int tid = threadIdx.x;
  const int w = tid >> 6, l = tid & 63;
  const int wm = w & 1, wn = w >> 1;
  const int lr = l >> 3, cl = l & 7;
  const int fr = l & 15, q4 = l >> 4;
  const int fc = fr;

  floatx4 acc[2][4];
#pragma unroll
  for (int mi = 0; mi < 2; ++mi)
#pragma unroll
    for (int ni = 0; ni < 4; ++ni)
#pragma unroll
      for (int r = 0; r < 4; ++r) acc[mi][ni][r] = 0.0f;

  for (int k0 = 0; k0 < CDIM; k0 += 64) {
#pragma unroll
    for (int i = 0; i < 2; ++i) {
      int row = i * 32 + w * 8 + lr;
      int cg = cl ^ (row & 7);
      gl2lds16(Ab + (size_t)(bM * 64 + row) * CDIM + k0 + cg * 8,
               As + row * 64 + cl * 8);
    }
#pragma unroll
    for (int i = 0; i < 4; ++i) {
      int row = i * 32 + w * 8 + lr;
      int cg = cl ^ (row & 7);
      gl2lds16(Wob + (size_t)(bN * 128 + row) * CDIM + k0 + cg * 8,
               Bs + row * 64 + cl * 8);
    }
    __syncthreads();
#pragma unroll
    for (int kk = 0; kk < 2; ++kk) {
      const int cgk = kk * 4 + q4;
      bf16x8 af[2], bfr[4];
#pragma unroll
      for (int mi = 0; mi < 2; ++mi) {
        int row = wm * 32 + mi * 16 + fr;
        af[mi] = *(const bf16x8*)(As + row * 64 + (cgk ^ (row & 7)) * 8);
      }
#pragma unroll
      for (int ni = 0; ni < 4; ++ni) {
        int row = wn * 64 + ni * 16 + fr;
        bfr[ni] = *(const bf16x8*)(Bs + row * 64 + (cgk ^ (row & 7)) * 8);
      }
#pragma unroll
      for (int mi = 0; mi < 2; ++mi)
#pragma unroll
        for (int ni = 0; ni < 4; ++ni)
          acc[mi][ni] = MFMA_16x16x32(af[mi], bfr[ni], acc[mi][ni]);
    }
    __syncthreads();
  }

#pragma unroll
  for (int ni = 0; ni < 4; ++ni) {
    int j = bN * 128 + wn * 64 + ni * 16 + fc;
    float bias = bo[j];
#pragma unroll
    for (int mi = 0; mi < 2; ++mi)
#pragma unroll
      for (int r = 0; r < 4; ++r) {
        int n = bM * 64 + wm * 32 + mi * 16 + q4 * 4 + r;
        Y[(size_t)n * CDIM + j] = acc[mi][ni][r] + bias;
      }
  }
}

// ---------------------------------------------------------------------------
extern "C" void kernel_launch(void* const* d_in, const int* in_sizes, int n_in,
                              void* d_out, int out_size, void* d_ws, size_t ws_size,
                              hipStream_t stream) {
  const float* x  = (const float*)d_in[0];
  const float* Wq = (const float*)d_in[1];
  const float* bq = (const float*)d_in[2];
  const float* Wk = (const float*)d_in[3];
  const float* bk = (const float*)d_in[4];
  const float* Wv = (const float*)d_in[5];
  const float* bv = (const float*)d_in[6];
  const float* Wo = (const float*)d_in[7];
  const float* bo = (const float*)d_in[8];
  float* Y = (float*)d_out;

  char* ws = (char*)d_ws;
  const size_t MB = 1024 * 1024;
  bf16* Xb    = (bf16*)(ws + 0);        //  8 MB  [4096,1024]
  bf16* Wqkvb = (bf16*)(ws + 8 * MB);   //  6 MB  [3072,1024]
  bf16* Wob   = (bf16*)(ws + 14 * MB);  //  2 MB  [1024,1024]
  bf16* Qb    = (bf16*)(ws + 16 * MB);  //  8 MB  [B,H,T,D] (pre-scaled, log2 domain)
  bf16* Kb    = (bf16*)(ws + 24 * MB);  //  8 MB  [B,H,T,D]
  bf16* Vtb   = (bf16*)(ws + 32 * MB);  //  8 MB  [B,H,D,T]
  bf16* Ao    = Xb;                     //  reuse: Xb dead after gemm_qkv

  convert_kernel<<<8192, 256, 0, stream>>>(x, Wq, Wk, Wv, Wo, Xb, Wqkvb, Wob);
  gemm_qkv<<<32 * 24, 256, 0, stream>>>(Xb, Wqkvb, bq, bk, bv, Qb, Kb, Vtb);
  flash_attn<<<dim3(32, 32), 256, 0, stream>>>(Qb, Kb, Vtb, Ao);
  gemm_out<<<64 * 8, 256, 0, stream>>>(Ao, Wob, bo, Y);
}

// Round 5
// 182.393 us; speedup vs baseline: 1.1428x; 1.0374x over previous
//
#include <hip/hip_runtime.h>
#include <hip/hip_bf16.h>
#include <stdint.h>
#include <stddef.h>

// DecoderAttention: B=2,T=2048,C=1024,H=16,D=64, causal, p=0.0
// R5: projection GEMMs were latency-bound at 2-3 blocks/CU (all pipes <21%).
//     gemm_qkv -> 64x128 tiles (1536 blocks = 6/CU, 24 KB LDS) and
//     gemm_out -> 64x64 tiles (1024 blocks = 4/CU, 16 KB LDS): more
//     independent staging pipelines per CU to hide the HBM->LDS->MFMA chain.
//     flash (R4 64-row + longest-first) and convert unchanged.

typedef __bf16 bf16;
typedef __attribute__((ext_vector_type(8))) __bf16 bf16x8;
typedef __attribute__((ext_vector_type(4))) __bf16 bf16x4;
typedef __attribute__((ext_vector_type(4))) float floatx4;

#define MFMA_16x16x32(A, B, C) __builtin_amdgcn_mfma_f32_16x16x32_bf16(A, B, C, 0, 0, 0)

static constexpr int T_SEQ = 2048;
static constexpr int CDIM  = 1024;

// async 16B global->LDS. LDS dest MUST be wave-uniform-base + lane*16.
__device__ __forceinline__ void gl2lds16(const bf16* g, bf16* l) {
  __builtin_amdgcn_global_load_lds(
      (const __attribute__((address_space(1))) uint32_t*)g,
      (__attribute__((address_space(3))) uint32_t*)l, 16, 0, 0);
}

// ---------------------------------------------------------------------------
// fp32 -> bf16 conversion / packing.
__global__ __launch_bounds__(256) void convert_kernel(
    const float* __restrict__ x, const float* __restrict__ Wq,
    const float* __restrict__ Wk, const float* __restrict__ Wv,
    const float* __restrict__ Wo,
    bf16* __restrict__ Xb, bf16* __restrict__ Wqkvb, bf16* __restrict__ Wob) {
  size_t i = ((size_t)blockIdx.x * 256 + threadIdx.x) * 4;  // 8388608 total elems
  const float* src;
  bf16* dst;
  size_t off;
  if (i < 4194304) {
    src = x; dst = Xb; off = i;
  } else {
    size_t r = i - 4194304;
    int wsel = (int)(r >> 20);
    off = r & 1048575;
    src = (wsel == 0) ? Wq : (wsel == 1) ? Wk : (wsel == 2) ? Wv : Wo;
    dst = (wsel < 3) ? (Wqkvb + ((size_t)wsel << 20)) : Wob;
  }
  float4 v = *(const float4*)(src + off);
  bf16x4 o;
  o[0] = (bf16)v.x; o[1] = (bf16)v.y; o[2] = (bf16)v.z; o[3] = (bf16)v.w;
  *(bf16x4*)(dst + off) = o;
}

// ---------------------------------------------------------------------------
// Kernel 2: fused QKV projection, 64x128 tiles, coalesced epilogue via LDS.
// Q pre-scaled by (1/8)*log2(e); V stored transposed [B,H,D,T].
__global__ __launch_bounds__(256) void gemm_qkv(
    const bf16* __restrict__ Xb, const bf16* __restrict__ Wqkvb,
    const float* __restrict__ bq, const float* __restrict__ bk,
    const float* __restrict__ bv,
    bf16* __restrict__ Qb, bf16* __restrict__ Kb, bf16* __restrict__ Vtb) {
  __shared__ __align__(16) bf16 smem[12288];  // 24 KB: As(4096)+Bs(8192) / Cs
  bf16* As = smem;          // 64 x 64
  bf16* Bs = smem + 4096;   // 128 x 64
  bf16* Cs = smem;          // overlay after final barrier

  const int bM = blockIdx.x & 63;   // 64 M-tiles of 64 rows (4096)
  const int bN = blockIdx.x >> 6;   // 24 N-tiles of 128 cols (3072)
  const int tid = threadIdx.x;
  const int w = tid >> 6, l = tid & 63;
  const int wm = w & 1, wn = w >> 1;   // wave tile: 32 rows x 64 cols
  const int lr = l >> 3, cl = l & 7;
  const int fr = l & 15, q4 = l >> 4;
  const int fc = fr;

  floatx4 acc[2][4];
#pragma unroll
  for (int mi = 0; mi < 2; ++mi)
#pragma unroll
    for (int ni = 0; ni < 4; ++ni)
#pragma unroll
      for (int r = 0; r < 4; ++r) acc[mi][ni][r] = 0.0f;

  for (int k0 = 0; k0 < CDIM; k0 += 64) {
#pragma unroll
    for (int i = 0; i < 2; ++i) {
      int row = i * 32 + w * 8 + lr;
      int cg = cl ^ (row & 7);
      gl2lds16(Xb + (size_t)(bM * 64 + row) * CDIM + k0 + cg * 8,
               As + row * 64 + cl * 8);
    }
#pragma unroll
    for (int i = 0; i < 4; ++i) {
      int row = i * 32 + w * 8 + lr;
      int cg = cl ^ (row & 7);
      gl2lds16(Wqkvb + (size_t)(bN * 128 + row) * CDIM + k0 + cg * 8,
               Bs + row * 64 + cl * 8);
    }
    __syncthreads();
#pragma unroll
    for (int kk = 0; kk < 2; ++kk) {
      const int cgk = kk * 4 + q4;
      bf16x8 af[2], bfr[4];
#pragma unroll
      for (int mi = 0; mi < 2; ++mi) {
        int row = wm * 32 + mi * 16 + fr;
        af[mi] = *(const bf16x8*)(As + row * 64 + (cgk ^ (row & 7)) * 8);
      }
#pragma unroll
      for (int ni = 0; ni < 4; ++ni) {
        int row = wn * 64 + ni * 16 + fr;
        bfr[ni] = *(const bf16x8*)(Bs + row * 64 + (cgk ^ (row & 7)) * 8);
      }
#pragma unroll
      for (int mi = 0; mi < 2; ++mi)
#pragma unroll
        for (int ni = 0; ni < 4; ++ni)
          acc[mi][ni] = MFMA_16x16x32(af[mi], bfr[ni], acc[mi][ni]);
    }
    __syncthreads();
  }

  const int seg = bN >> 3;  // 0=Q, 1=K, 2=V (uniform per block)
  const float QSCALE = 0.125f * 1.44269504089f;
  const float* bp = (seg == 0) ? bq : (seg == 1) ? bk : bv;

  // acc (C-layout) -> Cs. Q/K: Cs[tt(64)][j(128)] stride 136; V: Cs[j(128)][tt(64)] stride 72.
#pragma unroll
  for (int ni = 0; ni < 4; ++ni) {
    int jl = wn * 64 + ni * 16 + fc;
    float bias = bp[(bN * 128 + jl) & 1023];
#pragma unroll
    for (int mi = 0; mi < 2; ++mi)
#pragma unroll
      for (int r = 0; r < 4; ++r) {
        int ttl = wm * 32 + mi * 16 + q4 * 4 + r;
        float val = acc[mi][ni][r] + bias;
        if (seg == 0) val *= QSCALE;
        int addr = (seg == 2) ? jl * 72 + ttl : ttl * 136 + jl;
        Cs[addr] = (bf16)val;
      }
  }
  __syncthreads();

  if (seg < 2) {
    bf16* basep = (seg == 0) ? Qb : Kb;
    const int chunk = tid & 15;      // 16 chunks x 8 = 128 j
    const int rb = (tid >> 4) * 4;   // 16 groups x 4 rows = 64 tt
#pragma unroll
    for (int u = 0; u < 4; ++u) {
      int maj = rb + u;  // tt_local
      bf16x8 vdat = *(const bf16x8*)(Cs + maj * 136 + chunk * 8);
      int n = bM * 64 + maj;
      int b = n >> 11, tt = n & 2047;
      int j = bN * 128 + chunk * 8;
      int h = (j >> 6) & 15, d = j & 63;
      *(bf16x8*)(basep + (((size_t)(b * 16 + h) * T_SEQ + tt) << 6) + d) = vdat;
    }
  } else {
    const int chunk = tid & 7;       // 8 chunks x 8 = 64 tt
    const int rb = (tid >> 3) * 4;   // 32 groups x 4 rows = 128 j
#pragma unroll
    for (int u = 0; u < 4; ++u) {
      int maj = rb + u;  // j_local
      bf16x8 vdat = *(const bf16x8*)(Cs + maj * 72 + chunk * 8);
      int j = bN * 128 + maj;
      int h = (j >> 6) & 15, d = j & 63;
      int n0 = bM * 64 + chunk * 8;
      int b = n0 >> 11, tt0 = n0 & 2047;
      *(bf16x8*)(Vtb + ((size_t)(b * 16 + h) * 64 + d) * T_SEQ + tt0) = vdat;
    }
  }
}

// ---------------------------------------------------------------------------
// Kernel 3: causal flash attention, no-max exp2 softmax, Q-tile = 64 rows.
// Grid (B*H, T/64), longest-first: qt = 31 - blockIdx.y.
__global__ __launch_bounds__(256) void flash_attn(
    const bf16* __restrict__ Qb, const bf16* __restrict__ Kb,
    const bf16* __restrict__ Vtb, bf16* __restrict__ Ao) {
  __shared__ __align__(16) bf16 Ks[64 * 64];
  __shared__ __align__(16) bf16 Vs[64 * 64];
  __shared__ __align__(16) bf16 Ps[4][16 * 72];  // +8 pad

  const int bh = blockIdx.x;            // 0..31 = b*16+h
  const int qt = 31 - blockIdx.y;       // longest blocks dispatch first
  const int b = bh >> 4, h = bh & 15;
  const int tid = threadIdx.x;
  const int w = tid >> 6, l = tid & 63;
  const int fc = l & 15, q4 = l >> 4;
  const int lr = l >> 3, cl = l & 7;

  const bf16* Qg = Qb + (size_t)bh * T_SEQ * 64;
  const bf16* Kg = Kb + (size_t)bh * T_SEQ * 64;
  const bf16* Vg = Vtb + (size_t)bh * 64 * T_SEQ;

  // Q A-frags, loaded once (already scaled by (1/8)*log2e)
  const int qrow = qt * 64 + w * 16 + fc;
  bf16x8 qf[2];
  qf[0] = *(const bf16x8*)(Qg + (size_t)qrow * 64 + q4 * 8);
  qf[1] = *(const bf16x8*)(Qg + (size_t)qrow * 64 + 32 + q4 * 8);

  bf16x8 ones;
#pragma unroll
  for (int i = 0; i < 8; ++i) ones[i] = (bf16)1.0f;

  floatx4 o[4];
  floatx4 lacc;  // row-sum of P via MFMA ones-trick
#pragma unroll
  for (int ds = 0; ds < 4; ++ds)
#pragma unroll
    for (int r = 0; r < 4; ++r) o[ds][r] = 0.0f;
#pragma unroll
  for (int r = 0; r < 4; ++r) lacc[r] = 0.0f;

  for (int kv = 0; kv <= qt; ++kv) {
    const int kvbase = kv * 64;
#pragma unroll
    for (int i = 0; i < 2; ++i) {
      int row = i * 32 + w * 8 + lr;
      int cg = cl ^ (row & 7);
      gl2lds16(Kg + (size_t)(kvbase + row) * 64 + cg * 8, Ks + row * 64 + cl * 8);
      gl2lds16(Vg + (size_t)row * T_SEQ + kvbase + cg * 8, Vs + row * 64 + cl * 8);
    }
    __syncthreads();

    // S = Q K^T  (16 q-rows x 64 kv-cols per wave), log2 domain
    floatx4 s[4];
#pragma unroll
    for (int ni = 0; ni < 4; ++ni)
#pragma unroll
      for (int r = 0; r < 4; ++r) s[ni][r] = 0.0f;
#pragma unroll
    for (int kk = 0; kk < 2; ++kk) {
      const int cgk = kk * 4 + q4;
#pragma unroll
      for (int ni = 0; ni < 4; ++ni) {
        int row = ni * 16 + fc;
        bf16x8 kf = *(const bf16x8*)(Ks + row * 64 + (cgk ^ (row & 7)) * 8);
        s[ni] = MFMA_16x16x32(qf[kk], kf, s[ni]);
      }
    }

    // P = exp2(S) (no max: logits O(10), fp32-safe, shift-invariance exact);
    // masked entries p = 0. Write P to LDS in C-layout for A-frag re-read.
    if (kv == qt) {
      int qc = w * 16 + q4 * 4;
#pragma unroll
      for (int ni = 0; ni < 4; ++ni)
#pragma unroll
        for (int r = 0; r < 4; ++r) {
          int kc = ni * 16 + fc;
          float p = (kc > qc + r) ? 0.0f : __builtin_amdgcn_exp2f(s[ni][r]);
          Ps[w][(q4 * 4 + r) * 72 + ni * 16 + fc] = (bf16)p;
        }
    } else {
#pragma unroll
      for (int ni = 0; ni < 4; ++ni)
#pragma unroll
        for (int r = 0; r < 4; ++r)
          Ps[w][(q4 * 4 + r) * 72 + ni * 16 + fc] =
              (bf16)__builtin_amdgcn_exp2f(s[ni][r]);
    }

    // O += P V ; l += P 1  (row-sum on the idle MFMA pipe)
#pragma unroll
    for (int kk = 0; kk < 2; ++kk) {
      bf16x8 pf = *(const bf16x8*)(&Ps[w][fc * 72 + kk * 32 + q4 * 8]);
      const int cgk = kk * 4 + q4;
#pragma unroll
      for (int ds = 0; ds < 4; ++ds) {
        int row = ds * 16 + fc;
        bf16x8 vf = *(const bf16x8*)(Vs + row * 64 + (cgk ^ (row & 7)) * 8);
        o[ds] = MFMA_16x16x32(pf, vf, o[ds]);
      }
      lacc = MFMA_16x16x32(pf, ones, lacc);
    }
    __syncthreads();
  }

  // epilogue: O/l -> AttnOut[B,T,C] bf16
  float inv[4];
#pragma unroll
  for (int r = 0; r < 4; ++r) inv[r] = __builtin_amdgcn_rcpf(lacc[r]);
#pragma unroll
  for (int ds = 0; ds < 4; ++ds)
#pragma unroll
    for (int r = 0; r < 4; ++r) {
      int tt = qt * 64 + w * 16 + q4 * 4 + r;
      int col = h * 64 + ds * 16 + fc;
      Ao[((size_t)(b * T_SEQ + tt) << 10) + col] = (bf16)(o[ds][r] * inv[r]);
    }
}

// ---------------------------------------------------------------------------
// Kernel 4: output projection, 64x64 tiles (1024 blocks -> 4/CU), fp32 result
__global__ __launch_bounds__(256) void gemm_out(
    const bf16* __restrict__ Ab, const bf16* __restrict__ Wob,
    const float* __restrict__ bo, float* __restrict__ Y) {
  __shared__ __align__(16) bf16 As[64 * 64];   // 8 KB
  __shared__ __align__(16) bf16 Bs[64 * 64];   // 8 KB
  const int bM = blockIdx.x & 63;  // 64 M-tiles of 64 rows
  const int bN = blockIdx.x >> 6;  // 16 N-tiles of 64 cols
  const int tid = threadIdx.x;
  const int w = tid >> 6, l = tid & 63;
  const int wm = w & 1, wn = w >> 1;  // wave tile 32x32
  const int lr = l >> 3, cl = l & 7;
  const int fr = l & 15, q4 = l >> 4;
  const int fc = fr;

  floatx4 acc[2][2];
#pragma unroll
  for (int mi = 0; mi < 2; ++mi)
#pragma unroll
    for (int ni = 0; ni < 2; ++ni)
#pragma unroll
      for (int r = 0; r < 4; ++r) acc[mi][ni][r] = 0.0f;

  for (int k0 = 0; k0 < CDIM; k0 += 64) {
#pragma unroll
    for (int i = 0; i < 2; ++i) {
      int row = i * 32 + w * 8 + lr;
      int cg = cl ^ (row & 7);
      gl2lds16(Ab + (size_t)(bM * 64 + row) * CDIM + k0 + cg * 8,
               As + row * 64 + cl * 8);
      gl2lds16(Wob + (size_t)(bN * 64 + row) * CDIM + k0 + cg * 8,
               Bs + row * 64 + cl * 8);
    }
    __syncthreads();
#pragma unroll
    for (int kk = 0; kk < 2; ++kk) {
      const int cgk = kk * 4 + q4;
      bf16x8 af[2], bfr[2];
#pragma unroll
      for (int mi = 0; mi < 2; ++mi) {
        int row = wm * 32 + mi * 16 + fr;
        af[mi] = *(const bf16x8*)(As + row * 64 + (cgk ^ (row & 7)) * 8);
      }
#pragma unroll
      for (int ni = 0; ni < 2; ++ni) {
        int row = wn * 32 + ni * 16 + fr;
        bfr[ni] = *(const bf16x8*)(Bs + row * 64 + (cgk ^ (row & 7)) * 8);
      }
#pragma unroll
      for (int mi = 0; mi < 2; ++mi)
#pragma unroll
        for (int ni = 0; ni < 2; ++ni)
          acc[mi][ni] = MFMA_16x16x32(af[mi], bfr[ni], acc[mi][ni]);
    }
    __syncthreads();
  }

#pragma unroll
  for (int ni = 0; ni < 2; ++ni) {
    int j = bN * 64 + wn * 32 + ni * 16 + fc;
    float bias = bo[j];
#pragma unroll
    for (int mi = 0; mi < 2; ++mi)
#pragma unroll
      for (int r = 0; r < 4; ++r) {
        int n = bM * 64 + wm * 32 + mi * 16 + q4 * 4 + r;
        Y[(size_t)n * CDIM + j] = acc[mi][ni][r] + bias;
      }
  }
}

// ---------------------------------------------------------------------------
extern "C" void kernel_launch(void* const* d_in, const int* in_sizes, int n_in,
                              void* d_out, int out_size, void* d_ws, size_t ws_size,
                              hipStream_t stream) {
  const float* x  = (const float*)d_in[0];
  const float* Wq = (const float*)d_in[1];
  const float* bq = (const float*)d_in[2];
  const float* Wk = (const float*)d_in[3];
  const float* bk = (const float*)d_in[4];
  const float* Wv = (const float*)d_in[5];
  const float* bv = (const float*)d_in[6];
  const float* Wo = (const float*)d_in[7];
  const float* bo = (const float*)d_in[8];
  float* Y = (float*)d_out;

  char* ws = (char*)d_ws;
  const size_t MB = 1024 * 1024;
  bf16* Xb    = (bf16*)(ws + 0);        //  8 MB  [4096,1024]
  bf16* Wqkvb = (bf16*)(ws + 8 * MB);   //  6 MB  [3072,1024]
  bf16* Wob   = (bf16*)(ws + 14 * MB);  //  2 MB  [1024,1024]
  bf16* Qb    = (bf16*)(ws + 16 * MB);  //  8 MB  [B,H,T,D] (pre-scaled, log2 domain)
  bf16* Kb    = (bf16*)(ws + 24 * MB);  //  8 MB  [B,H,T,D]
  bf16* Vtb   = (bf16*)(ws + 32 * MB);  //  8 MB  [B,H,D,T]
  bf16* Ao    = Xb;                     //  reuse: Xb dead after gemm_qkv

  convert_kernel<<<8192, 256, 0, stream>>>(x, Wq, Wk, Wv, Wo, Xb, Wqkvb, Wob);
  gemm_qkv<<<64 * 24, 256, 0, stream>>>(Xb, Wqkvb, bq, bk, bv, Qb, Kb, Vtb);
  flash_attn<<<dim3(32, 32), 256, 0, stream>>>(Qb, Kb, Vtb, Ao);
  gemm_out<<<64 * 16, 256, 0, stream>>>(Ao, Wob, bo, Y);
}